// Round 16
// baseline (233.413 us; speedup 1.0000x reference)
//
#include <hip/hip_runtime.h>
#include <hip/hip_bf16.h>
#include <math.h>

#define HID 64
#define NBA 512        // phase A/B blocks
#define NBUCK 256      // buckets (key>>9)
#define BSHIFT 9
#define BINS 512       // nodes per bucket
#define NBN (NBUCK * NBA)   // 131072 counters per side
#define RSTRIDE 36     // u32 per table row: 32 bf16x2 (64ch) + 2 fp32 x + 2 pad

typedef __attribute__((ext_vector_type(8))) short bf16x8;
typedef __attribute__((ext_vector_type(4))) float f32x4;

// ---- bf16 pack/unpack (RNE) ----
__device__ __forceinline__ unsigned int bf16r(float f) {
    unsigned int u = __float_as_uint(f);
    return (u + 0x7fffu + ((u >> 16) & 1u)) >> 16;
}
__device__ __forceinline__ unsigned int pack2(float a, float b) {
    return bf16r(a) | (bf16r(b) << 16);
}
__device__ __forceinline__ float lo2f(unsigned int u) { return __uint_as_float(u << 16); }
__device__ __forceinline__ float hi2f(unsigned int u) { return __uint_as_float(u & 0xffff0000u); }

__device__ __forceinline__ bf16x8 asbf(uint4 u) {
    union { uint4 u4; bf16x8 b; } c; c.u4 = u; return c.b;
}
__device__ __forceinline__ void load8(const float* p, float* d) {
    float4 a = *(const float4*)p, b = *(const float4*)(p + 4);
    d[0]=a.x; d[1]=a.y; d[2]=a.z; d[3]=a.w; d[4]=b.x; d[5]=b.y; d[6]=b.z; d[7]=b.w;
}

// ---------------- phase A: per-block bucket counts (LDS only) ----------------
__global__ void bucketA_kernel(const int* __restrict__ ei, int E,
                               int* __restrict__ cntsc) {
    __shared__ int cd[NBUCK], cs[NBUCK];
    int t = threadIdx.x;
    cd[t] = 0; cs[t] = 0;
    __syncthreads();
    int ce = (E + NBA - 1) / NBA;
    int e0 = blockIdx.x * ce, e1 = min(e0 + ce, E);
    for (int e = e0 + t; e < e1; e += 256) {
        int s = ei[e], d = ei[E + e];
        atomicAdd(&cs[s >> BSHIFT], 1);
        atomicAdd(&cd[d >> BSHIFT], 1);
    }
    __syncthreads();
    cntsc[t * NBA + blockIdx.x]       = cd[t];   // dst side [0, NBN)
    cntsc[NBN + t * NBA + blockIdx.x] = cs[t];   // src side [NBN, 2*NBN)
}

// ---------------- 3-kernel exclusive scan (generic, n = 2*NBN) ---------------
__global__ void scanA_kernel(const int* __restrict__ cnt, int* __restrict__ bs, int N) {
    __shared__ int s[256];
    int t = threadIdx.x, n = blockIdx.x * 256 + t;
    s[t] = (n < N) ? cnt[n] : 0;
    __syncthreads();
    for (int off = 128; off > 0; off >>= 1) {
        if (t < off) s[t] += s[t + off];
        __syncthreads();
    }
    if (t == 0) bs[blockIdx.x] = s[0];
}

__global__ void scanB_kernel(int* __restrict__ bs, int nb) {
    __shared__ int s[1024];
    int t = threadIdx.x;
    int orig = (t < nb) ? bs[t] : 0;
    s[t] = orig;
    __syncthreads();
    for (int off = 1; off < 1024; off <<= 1) {
        int v = (t >= off) ? s[t - off] : 0;
        __syncthreads();
        s[t] += v;
        __syncthreads();
    }
    if (t < nb) bs[t] = s[t] - orig;   // exclusive
}

__global__ void scanC_kernel(const int* __restrict__ cnt, const int* __restrict__ bs,
                             int* __restrict__ outp, int N) {
    __shared__ int s[256];
    int t = threadIdx.x, n = blockIdx.x * 256 + t;
    int c = (n < N) ? cnt[n] : 0;
    s[t] = c;
    __syncthreads();
    for (int off = 1; off < 256; off <<= 1) {
        int v = (t >= off) ? s[t - off] : 0;
        __syncthreads();
        s[t] += v;
        __syncthreads();
    }
    if (n < N) outp[n] = bs[blockIdx.x] + s[t] - c;
}

// ---------------- phase B: scatter packed records into bucket regions --------
// dstrec u32 = src | (dstbin << 17)   (src < 2^17, bin 9 bits)
__global__ void bucketB_kernel(const int* __restrict__ ei, int E,
                               const int* __restrict__ scanned,
                               unsigned int* __restrict__ dstrec,
                               int* __restrict__ srckeys) {
    __shared__ int cd[NBUCK], cs[NBUCK], bd[NBUCK], bsr[NBUCK];
    int t = threadIdx.x;
    cd[t] = 0; cs[t] = 0;
    bd[t]  = scanned[t * NBA + blockIdx.x];
    bsr[t] = scanned[NBN + t * NBA + blockIdx.x] - E;
    __syncthreads();
    int ce = (E + NBA - 1) / NBA;
    int e0 = blockIdx.x * ce, e1 = min(e0 + ce, E);
    for (int e = e0 + t; e < e1; e += 256) {
        int s = ei[e], d = ei[E + e];
        int db = d >> BSHIFT, sb = s >> BSHIFT;
        int rd = atomicAdd(&cd[db], 1);
        dstrec[bd[db] + rd] = (unsigned int)s | ((unsigned int)(d & (BINS - 1)) << 17);
        int rs = atomicAdd(&cs[sb], 1);
        srckeys[bsr[sb] + rs] = s;
    }
}

// ---------------- phase C2: per-bucket src counts -> dinv --------------------
__global__ void bucketC2_kernel(const int* __restrict__ srckeys,
                                const int* __restrict__ scanned,
                                float* __restrict__ dinv, int N, int E) {
    __shared__ int deg[BINS];
    int b = blockIdx.x, t = threadIdx.x;   // 512 threads
    deg[t] = 0;
    __syncthreads();
    int start = scanned[NBN + b * NBA] - E;
    int end   = (b < NBUCK - 1) ? scanned[NBN + (b + 1) * NBA] - E : E;
    for (int i = start + t; i < end; i += BINS)
        atomicAdd(&deg[srckeys[i] & (BINS - 1)], 1);
    __syncthreads();
    int node = (b << BSHIFT) + t;
    if (node < N) {
        int dg = deg[t];
        dinv[node] = dg > 0 ? rsqrtf((float)dg) : 0.0f;
    }
}

// ---------------- phase C1: per-bucket CSR (row, cnt, srcw) ------------------
__global__ void bucketC1_kernel(const unsigned int* __restrict__ dstrec,
                                const int* __restrict__ scanned,
                                const float* __restrict__ dinv,
                                int* __restrict__ row, int* __restrict__ cnt,
                                int2* __restrict__ srcw, int N, int E) {
    __shared__ int lc[BINS], ls[BINS], lr[BINS];
    int b = blockIdx.x, t = threadIdx.x;   // 512 threads
    lc[t] = 0; lr[t] = 0;
    __syncthreads();
    int start = scanned[b * NBA];
    int end   = (b < NBUCK - 1) ? scanned[(b + 1) * NBA] : E;
    for (int i = start + t; i < end; i += BINS)
        atomicAdd(&lc[dstrec[i] >> 17], 1);
    __syncthreads();
    // inclusive scan of lc (Hillis-Steele, 512 threads)
    ls[t] = lc[t];
    __syncthreads();
    for (int off = 1; off < BINS; off <<= 1) {
        int v = (t >= off) ? ls[t - off] : 0;
        __syncthreads();
        ls[t] += v;
        __syncthreads();
    }
    int rl = start + ls[t] - lc[t];   // exclusive -> global row
    int node = (b << BSHIFT) + t;
    if (node < N) { row[node] = rl; cnt[node] = lc[t]; }
    __syncthreads();
    ls[t] = rl;                        // reuse as scatter base
    __syncthreads();
    for (int i = start + t; i < end; i += BINS) {
        unsigned int rec = dstrec[i];
        int bin = (int)(rec >> 17);
        int src = (int)(rec & 0x1FFFFu);
        int p = ls[bin] + atomicAdd(&lr[bin], 1);
        srcw[p] = make_int2(src, __float_as_int(dinv[src]));
    }
}

// ---------------- pack transposed bf16 weight tables -------------------------
__global__ void packwT_kernel(const float* __restrict__ W2, const float* __restrict__ Wz,
                              const float* __restrict__ Wr, const float* __restrict__ Wc,
                              unsigned int* __restrict__ WT) {
    int idx = blockIdx.x * blockDim.x + threadIdx.x;
    if (idx >= 18432) return;
    float v0, v1;
    if (idx < 6144) {
        int c = idx / 96, kk = idx % 96;
        int k0 = 2 * kk;
        if (k0 < 64) {
            v0 = W2[k0 * 64 + c] - W2[8192 + k0 * 64 + c];
            v1 = W2[(k0 + 1) * 64 + c] - W2[8192 + (k0 + 1) * 64 + c];
        } else if (k0 < 128) {
            v0 = W2[4096 + (k0 - 64) * 64 + c];
            v1 = W2[4096 + (k0 - 63) * 64 + c];
        } else {
            v0 = 2.0f * W2[8192 + (k0 - 128) * 64 + c];
            v1 = 2.0f * W2[8192 + (k0 - 127) * 64 + c];
        }
    } else if (idx < 14336) {
        int t = idx - 6144;
        int c = t / 64, kk = t % 64, k0 = 2 * kk;
        const float* Ws = (c < 64) ? Wz : Wr;
        int cc = c & 63;
        v0 = Ws[k0 * 64 + cc];
        v1 = Ws[(k0 + 1) * 64 + cc];
    } else {
        int t = idx - 14336;
        int c = t / 64, kk = t % 64, k0 = 2 * kk;
        v0 = Wc[k0 * 64 + c];
        v1 = Wc[(k0 + 1) * 64 + c];
    }
    WT[idx] = pack2(v0, v1);
}

// ---------------- pack [h (bf16) | x (fp32)] -> fused table ------------------
__global__ void packh_kernel(const float* __restrict__ h, const float* __restrict__ x,
                             unsigned int* __restrict__ tab, int N) {
    int i = blockIdx.x * blockDim.x + threadIdx.x;   // over 34N words
    if (i >= 34 * N) return;
    int n = i / 34, w = i - n * 34;
    unsigned int* rowp = tab + (size_t)n * RSTRIDE;
    if (w < 32) {
        float2 v = ((const float2*)h)[n * 32 + w];
        rowp[w] = pack2(v.x, v.y);
    } else {
        rowp[w] = __float_as_uint(x[2 * n + (w - 32)]);
    }
}

// ---------------- fused 64ch-bf16 + 2ch-fp32 gather propagation --------------
// wave per node; 8 edge slots x 8 lanes; channels via uint4, x-pair via fp32.
__global__ void gather64_kernel(const int* __restrict__ row, const int* __restrict__ cnt,
                                const int2* __restrict__ srcw, const float* __restrict__ dinv,
                                const unsigned int* __restrict__ src,  // RSTRIDE u32/row
                                unsigned int* __restrict__ dst, int N) {
    int wu = __builtin_amdgcn_readfirstlane((int)threadIdx.x >> 6);
    int n = blockIdx.x * 4 + wu;
    if (n >= N) return;
    int lane = threadIdx.x & 63;
    int t    = lane & 7;      // u32 quad within row (channels 8t..8t+7)
    int slot = lane >> 3;     // edge slot 0..7
    int start = row[n], k = cnt[n];
    float a0 = 0, a1 = 0, a2 = 0, a3 = 0, a4 = 0, a5 = 0, a6 = 0, a7 = 0;
    float ax0 = 0, ax1 = 0;
    for (int e = slot; e < k; e += 16) {   // 2 edges in flight per lane-group
        int2 rec0 = srcw[start + e];
        bool h2 = (e + 8) < k;
        int2 rec1 = h2 ? srcw[start + e + 8] : rec0;
        const unsigned int* r0 = src + (size_t)rec0.x * RSTRIDE;
        const unsigned int* r1 = src + (size_t)rec1.x * RSTRIDE;
        uint4 v0 = ((const uint4*)r0)[t];
        uint4 v1 = ((const uint4*)r1)[t];
        float2 xv0 = *(const float2*)(r0 + 32);
        float2 xv1 = *(const float2*)(r1 + 32);
        float w0 = __int_as_float(rec0.y);
        float w1 = h2 ? __int_as_float(rec1.y) : 0.0f;
        a0 = fmaf(w0, lo2f(v0.x), a0); a1 = fmaf(w0, hi2f(v0.x), a1);
        a2 = fmaf(w0, lo2f(v0.y), a2); a3 = fmaf(w0, hi2f(v0.y), a3);
        a4 = fmaf(w0, lo2f(v0.z), a4); a5 = fmaf(w0, hi2f(v0.z), a5);
        a6 = fmaf(w0, lo2f(v0.w), a6); a7 = fmaf(w0, hi2f(v0.w), a7);
        ax0 = fmaf(w0, xv0.x, ax0);    ax1 = fmaf(w0, xv0.y, ax1);
        a0 = fmaf(w1, lo2f(v1.x), a0); a1 = fmaf(w1, hi2f(v1.x), a1);
        a2 = fmaf(w1, lo2f(v1.y), a2); a3 = fmaf(w1, hi2f(v1.y), a3);
        a4 = fmaf(w1, lo2f(v1.z), a4); a5 = fmaf(w1, hi2f(v1.z), a5);
        a6 = fmaf(w1, lo2f(v1.w), a6); a7 = fmaf(w1, hi2f(v1.w), a7);
        ax0 = fmaf(w1, xv1.x, ax0);    ax1 = fmaf(w1, xv1.y, ax1);
    }
    a0 += __shfl_xor(a0, 8);  a1 += __shfl_xor(a1, 8);
    a2 += __shfl_xor(a2, 8);  a3 += __shfl_xor(a3, 8);
    a4 += __shfl_xor(a4, 8);  a5 += __shfl_xor(a5, 8);
    a6 += __shfl_xor(a6, 8);  a7 += __shfl_xor(a7, 8);
    ax0 += __shfl_xor(ax0, 8);  ax1 += __shfl_xor(ax1, 8);
    a0 += __shfl_xor(a0, 16); a1 += __shfl_xor(a1, 16);
    a2 += __shfl_xor(a2, 16); a3 += __shfl_xor(a3, 16);
    a4 += __shfl_xor(a4, 16); a5 += __shfl_xor(a5, 16);
    a6 += __shfl_xor(a6, 16); a7 += __shfl_xor(a7, 16);
    ax0 += __shfl_xor(ax0, 16); ax1 += __shfl_xor(ax1, 16);
    a0 += __shfl_xor(a0, 32); a1 += __shfl_xor(a1, 32);
    a2 += __shfl_xor(a2, 32); a3 += __shfl_xor(a3, 32);
    a4 += __shfl_xor(a4, 32); a5 += __shfl_xor(a5, 32);
    a6 += __shfl_xor(a6, 32); a7 += __shfl_xor(a7, 32);
    ax0 += __shfl_xor(ax0, 32); ax1 += __shfl_xor(ax1, 32);
    if (slot == 0) {
        float dn = -dinv[n];
        unsigned int* drow = dst + (size_t)n * RSTRIDE;
        uint4 o;
        o.x = pack2(dn * a0, dn * a1);
        o.y = pack2(dn * a2, dn * a3);
        o.z = pack2(dn * a4, dn * a5);
        o.w = pack2(dn * a6, dn * a7);
        ((uint4*)drow)[t] = o;
        if (t == 0)
            *(float2*)(drow + 32) = make_float2(dn * ax0, dn * ax1);
    }
}

// ---------------- MFMA fused input_conv + hidden_conv + GRU gates -----------
// Block = 4 waves (128 nodes), wave = 32 nodes (mt=2 ILP). WzrT+WcT staged in
// LDS (padded stride 68 -> <=2-way banks). txa/txb now read from fused table
// words 32-33 (fp32). W2eT (GEMM1) stays global.
__global__ __launch_bounds__(256, 2) void gate_mfma_kernel(
    float* __restrict__ out,
    const float* __restrict__ x,
    const float* __restrict__ h,
    const unsigned int* __restrict__ t1u,   // fused rows: [prop(h)|prop(x)]
    const unsigned int* __restrict__ ppu,   // fused rows: [prop2(h)|prop2(x)]
    const float* __restrict__ W1, const float* __restrict__ b1,
    const unsigned int* __restrict__ WT,
    const float* __restrict__ b2, const float* __restrict__ bz,
    const float* __restrict__ br, const float* __restrict__ bc,
    int N) {
    __shared__ __align__(16) unsigned int s_wzr[128 * 68];   // 34816 B
    __shared__ __align__(16) unsigned int s_wc [64 * 68];    // 17408 B
    __shared__ unsigned short tr[4][32][72];                 // 18432 B

    int tid  = threadIdx.x;
    int lane = tid & 63;
    int wu   = __builtin_amdgcn_readfirstlane(tid >> 6);
    int q    = lane >> 4;      // 0..3
    int r16  = lane & 15;
    int base = blockIdx.x * 128 + wu * 32;

    int nA[2];
    nA[0] = min(base + r16, N - 1);
    nA[1] = min(base + 16 + r16, N - 1);

    const unsigned int* W2eT = WT;

    // ---- stage WzrT (8192 u32) + WcT (4096 u32) into padded LDS ----
    {
        const uint4* wzr4 = (const uint4*)(WT + 6144);
        const uint4* wc4  = (const uint4*)(WT + 14336);
        #pragma unroll
        for (int i = 0; i < 8; ++i) {
            int idx4 = tid + i * 256;            // 0..2047 uint4
            uint4 v = wzr4[idx4];
            int r = idx4 >> 4, c4 = (idx4 & 15) * 4;
            *(uint4*)&s_wzr[r * 68 + c4] = v;
        }
        #pragma unroll
        for (int i = 0; i < 4; ++i) {
            int idx4 = tid + i * 256;            // 0..1023 uint4
            uint4 v = wc4[idx4];
            int r = idx4 >> 4, c4 = (idx4 & 15) * 4;
            *(uint4*)&s_wc[r * 68 + c4] = v;
        }
    }

    // ---- ic A-fragments (computed in frag layout on VALU) ----
    uint4 icA[2][2];
    {
        float2 xv[2], tav[2], tbv[2];
        #pragma unroll
        for (int mt = 0; mt < 2; ++mt) {
            xv[mt]  = ((const float2*)x)[nA[mt]];
            tav[mt] = *(const float2*)(t1u + (size_t)nA[mt] * RSTRIDE + 32);
            tbv[mt] = *(const float2*)(ppu + (size_t)nA[mt] * RSTRIDE + 32);
        }
        #pragma unroll
        for (int kf = 0; kf < 2; ++kf) {
            int ch0 = kf * 32 + 8 * q;
            float b1s[8], w0[8], w1s[8], w2[8], w3[8], w4[8], w5[8];
            load8(b1 + ch0, b1s);
            load8(W1 + ch0, w0);       load8(W1 + 64 + ch0, w1s);
            load8(W1 + 128 + ch0, w2); load8(W1 + 192 + ch0, w3);
            load8(W1 + 256 + ch0, w4); load8(W1 + 320 + ch0, w5);
            #pragma unroll
            for (int mt = 0; mt < 2; ++mt) {
                float t20 = 2.0f * tbv[mt].x - xv[mt].x;
                float t21 = 2.0f * tbv[mt].y - xv[mt].y;
                unsigned int pr[4];
                #pragma unroll
                for (int p = 0; p < 4; ++p) {
                    float v0 = b1s[2*p]   + xv[mt].x * w0[2*p]   + xv[mt].y * w1s[2*p]
                             + tav[mt].x * w2[2*p]   + tav[mt].y * w3[2*p]
                             + t20 * w4[2*p]   + t21 * w5[2*p];
                    float v1 = b1s[2*p+1] + xv[mt].x * w0[2*p+1] + xv[mt].y * w1s[2*p+1]
                             + tav[mt].x * w2[2*p+1] + tav[mt].y * w3[2*p+1]
                             + t20 * w4[2*p+1] + t21 * w5[2*p+1];
                    pr[p] = pack2(v0, v1);
                }
                icA[mt][kf] = make_uint4(pr[0], pr[1], pr[2], pr[3]);
            }
        }
    }

    // ---- GEMM1: hc = [h|t1|pp] @ W2eff  (K=192, 6 k-steps; B from global) ----
    f32x4 acc1[2][4];
    #pragma unroll
    for (int mt = 0; mt < 2; ++mt)
        #pragma unroll
        for (int nt = 0; nt < 4; ++nt)
            acc1[mt][nt] = (f32x4){0.0f, 0.0f, 0.0f, 0.0f};

    #pragma unroll
    for (int ks = 0; ks < 6; ++ks) {
        bf16x8 a[2];
        if (ks < 2) {
            #pragma unroll
            for (int mt = 0; mt < 2; ++mt) {
                float hs[8];
                load8(h + (size_t)nA[mt] * 64 + ks * 32 + 8 * q, hs);
                uint4 u;
                u.x = pack2(hs[0], hs[1]); u.y = pack2(hs[2], hs[3]);
                u.z = pack2(hs[4], hs[5]); u.w = pack2(hs[6], hs[7]);
                a[mt] = asbf(u);
            }
        } else {
            const unsigned int* tab = (ks < 4) ? t1u : ppu;
            int ksl = ks & 1;
            #pragma unroll
            for (int mt = 0; mt < 2; ++mt)
                a[mt] = asbf(*(const uint4*)(tab + (size_t)nA[mt] * RSTRIDE + ksl * 16 + q * 4));
        }
        #pragma unroll
        for (int nt = 0; nt < 4; ++nt) {
            bf16x8 b = asbf(*(const uint4*)(W2eT + (nt * 16 + r16) * 96 + ks * 16 + q * 4));
            #pragma unroll
            for (int mt = 0; mt < 2; ++mt)
                acc1[mt][nt] = __builtin_amdgcn_mfma_f32_16x16x32_bf16(a[mt], b, acc1[mt][nt], 0, 0, 0);
        }
    }

    __syncthreads();   // staged weights ready (overlapped with icA + GEMM1)

    // ---- add b2; per-wave LDS transpose hc -> A-frag layout ----
    float b2v[4];
    #pragma unroll
    for (int nt = 0; nt < 4; ++nt) b2v[nt] = b2[nt * 16 + r16];
    #pragma unroll
    for (int mt = 0; mt < 2; ++mt)
        #pragma unroll
        for (int nt = 0; nt < 4; ++nt)
            #pragma unroll
            for (int reg = 0; reg < 4; ++reg) {
                acc1[mt][nt][reg] += b2v[nt];
                tr[wu][mt * 16 + 4 * q + reg][nt * 16 + r16] =
                    (unsigned short)bf16r(acc1[mt][nt][reg]);
            }
    __builtin_amdgcn_wave_barrier();
    bf16x8 hcA[2][2];
    #pragma unroll
    for (int mt = 0; mt < 2; ++mt)
        #pragma unroll
        for (int kf = 0; kf < 2; ++kf)
            hcA[mt][kf] = asbf(*(const uint4*)&tr[wu][mt * 16 + r16][kf * 32 + 8 * q]);
    __builtin_amdgcn_wave_barrier();

    // ---- GEMM2: [z|r] = [ic|hc] @ [Wz|Wr]  (K=128, N=128; B from LDS) ----
    f32x4 acc2[2][8];
    #pragma unroll
    for (int mt = 0; mt < 2; ++mt)
        #pragma unroll
        for (int nt = 0; nt < 8; ++nt)
            acc2[mt][nt] = (f32x4){0.0f, 0.0f, 0.0f, 0.0f};

    #pragma unroll
    for (int kf = 0; kf < 4; ++kf) {
        bf16x8 a[2];
        a[0] = (kf < 2) ? asbf(icA[0][kf]) : hcA[0][kf - 2];
        a[1] = (kf < 2) ? asbf(icA[1][kf]) : hcA[1][kf - 2];
        #pragma unroll
        for (int nt = 0; nt < 8; ++nt) {
            bf16x8 b = asbf(*(const uint4*)&s_wzr[(nt * 16 + r16) * 68 + kf * 16 + q * 4]);
            #pragma unroll
            for (int mt = 0; mt < 2; ++mt)
                acc2[mt][nt] = __builtin_amdgcn_mfma_f32_16x16x32_bf16(a[mt], b, acc2[mt][nt], 0, 0, 0);
        }
    }

    // ---- gates: z = sig(az), r = sig(ar); transpose r*hc ----
    float bzv[4], brv[4];
    #pragma unroll
    for (int nt = 0; nt < 4; ++nt) { bzv[nt] = bz[nt * 16 + r16]; brv[nt] = br[nt * 16 + r16]; }
    float zz[2][4][4];
    #pragma unroll
    for (int mt = 0; mt < 2; ++mt)
        #pragma unroll
        for (int nt = 0; nt < 4; ++nt)
            #pragma unroll
            for (int reg = 0; reg < 4; ++reg) {
                zz[mt][nt][reg] = 1.0f / (1.0f + __expf(-(acc2[mt][nt][reg] + bzv[nt])));
                float rr = 1.0f / (1.0f + __expf(-(acc2[mt][nt + 4][reg] + brv[nt])));
                float rhc = rr * acc1[mt][nt][reg];
                tr[wu][mt * 16 + 4 * q + reg][nt * 16 + r16] = (unsigned short)bf16r(rhc);
            }
    __builtin_amdgcn_wave_barrier();
    bf16x8 rhcA[2][2];
    #pragma unroll
    for (int mt = 0; mt < 2; ++mt)
        #pragma unroll
        for (int kf = 0; kf < 2; ++kf)
            rhcA[mt][kf] = asbf(*(const uint4*)&tr[wu][mt * 16 + r16][kf * 32 + 8 * q]);
    __builtin_amdgcn_wave_barrier();

    // ---- GEMM3: cand = [ic|r*hc] @ Wc  (K=128, N=64; B from LDS) ----
    f32x4 acc3[2][4];
    #pragma unroll
    for (int mt = 0; mt < 2; ++mt)
        #pragma unroll
        for (int nt = 0; nt < 4; ++nt)
            acc3[mt][nt] = (f32x4){0.0f, 0.0f, 0.0f, 0.0f};

    #pragma unroll
    for (int kf = 0; kf < 4; ++kf) {
        bf16x8 a[2];
        a[0] = (kf < 2) ? asbf(icA[0][kf]) : rhcA[0][kf - 2];
        a[1] = (kf < 2) ? asbf(icA[1][kf]) : rhcA[1][kf - 2];
        #pragma unroll
        for (int nt = 0; nt < 4; ++nt) {
            bf16x8 b = asbf(*(const uint4*)&s_wc[(nt * 16 + r16) * 68 + kf * 16 + q * 4]);
            #pragma unroll
            for (int mt = 0; mt < 2; ++mt)
                acc3[mt][nt] = __builtin_amdgcn_mfma_f32_16x16x32_bf16(a[mt], b, acc3[mt][nt], 0, 0, 0);
        }
    }

    // ---- epilogue: out = z*h + (1-z)*tanh(cand + bc) ----
    float bcv[4];
    #pragma unroll
    for (int nt = 0; nt < 4; ++nt) bcv[nt] = bc[nt * 16 + r16];
    #pragma unroll
    for (int mt = 0; mt < 2; ++mt)
        #pragma unroll
        for (int nt = 0; nt < 4; ++nt)
            #pragma unroll
            for (int reg = 0; reg < 4; ++reg) {
                int node = base + mt * 16 + 4 * q + reg;
                if (node < N) {
                    float a = acc3[mt][nt][reg] + bcv[nt];
                    a = fminf(fmaxf(a, -40.0f), 40.0f);
                    float e = __expf(2.0f * a);
                    float ht = 1.0f - 2.0f / (e + 1.0f);
                    float hv = h[(size_t)node * 64 + nt * 16 + r16];
                    float z = zz[mt][nt][reg];
                    out[(size_t)node * 64 + nt * 16 + r16] = z * hv + (1.0f - z) * ht;
                }
            }
}

extern "C" void kernel_launch(void* const* d_in, const int* in_sizes, int n_in,
                              void* d_out, int out_size, void* d_ws, size_t ws_size,
                              hipStream_t stream) {
    const float* x  = (const float*)d_in[0];
    const int*   ei = (const int*)  d_in[1];
    const float* h  = (const float*)d_in[2];
    const float* W1 = (const float*)d_in[3];
    const float* b1 = (const float*)d_in[4];
    const float* W2 = (const float*)d_in[5];
    const float* b2 = (const float*)d_in[6];
    const float* Wz = (const float*)d_in[7];
    const float* bz = (const float*)d_in[8];
    const float* Wr = (const float*)d_in[9];
    const float* br = (const float*)d_in[10];
    const float* Wc = (const float*)d_in[11];
    const float* bc = (const float*)d_in[12];
    float* out = (float*)d_out;

    int N = in_sizes[0] / 2;     // 100000
    int E = in_sizes[1] / 2;     // 1600000

    // workspace layout (u32 units):
    //   dinv N | row N | cnt N | bs 1024 | WT 18432
    //   | cntsc 2*NBN | scanned 2*NBN | srcw 2E
    //   O: bufA 36N | hpp 36N    (dstrec E | srckeys E alias inside bufA span)
    char* wsb = (char*)d_ws;
    float* dinv = (float*)wsb;                                   // N
    int*   row  = (int*)  (wsb + (size_t)N * 4);                 // N
    int*   cnt  = (int*)  (wsb + (size_t)2 * N * 4);             // N
    int*   bs   = (int*)  (wsb + (size_t)3 * N * 4);             // 1024
    unsigned int* WT = (unsigned int*)(wsb + ((size_t)3 * N + 1024) * 4);      // 18432
    int*   cntsc   = (int*)(wsb + ((size_t)3 * N + 19456) * 4);                // 2*NBN
    int*   scanned = (int*)(wsb + ((size_t)3 * N + 19456 + 2 * NBN) * 4);      // 2*NBN
    int2*  srcw = (int2*)(wsb + ((size_t)3 * N + 19456 + 4 * NBN) * 4);        // 2E
    size_t O = (size_t)3 * N + 19456 + 4 * (size_t)NBN + 2 * (size_t)E;
    unsigned int* bufA = (unsigned int*)(wsb + O * 4);                         // 36N
    unsigned int* hpp  = (unsigned int*)(wsb + (O + (size_t)36 * N) * 4);      // 36N
    unsigned int* dstrec = (unsigned int*)(wsb + O * 4);                       // E (alias)
    int* srckeys = (int*)(wsb + (O + (size_t)E) * 4);                          // E (alias)

    // ---- bucketed CSR build (no global atomics, no memset) ----
    bucketA_kernel<<<NBA, 256, 0, stream>>>(ei, E, cntsc);
    int scn = 2 * NBN;
    scanA_kernel<<<scn / 256, 256, 0, stream>>>(cntsc, bs, scn);
    scanB_kernel<<<1, 1024, 0, stream>>>(bs, scn / 256);
    scanC_kernel<<<scn / 256, 256, 0, stream>>>(cntsc, bs, scanned, scn);
    bucketB_kernel<<<NBA, 256, 0, stream>>>(ei, E, scanned, dstrec, srckeys);
    bucketC2_kernel<<<NBUCK, BINS, 0, stream>>>(srckeys, scanned, dinv, N, E);
    bucketC1_kernel<<<NBUCK, BINS, 0, stream>>>(dstrec, scanned, dinv, row, cnt, srcw, N, E);

    // packs (hpp region does not overlap build temps; placed after for clarity)
    packwT_kernel<<<(18432 + 255) / 256, 256, 0, stream>>>(W2, Wz, Wr, Wc, WT);
    packh_kernel <<<(34 * N + 255) / 256, 256, 0, stream>>>(h, x, hpp, N);

    // fused hidden+input path: [h|x] -> bufA -> hpp (two gather passes)
    int gblocks = (N + 3) / 4;
    gather64_kernel<<<gblocks, 256, 0, stream>>>(row, cnt, srcw, dinv, hpp,  bufA, N);
    gather64_kernel<<<gblocks, 256, 0, stream>>>(row, cnt, srcw, dinv, bufA, hpp,  N);

    // fused MFMA gate (4 waves/block, 128 nodes; WzrT/WcT staged in LDS)
    int gateblocks = (N + 127) / 128;
    gate_mfma_kernel<<<gateblocks, 256, 0, stream>>>(
        out, x, h, bufA, hpp, W1, b1, WT, b2, bz, br, bc, N);
}

// Round 18
// 215.855 us; speedup vs baseline: 1.0813x; 1.0813x over previous
//
#include <hip/hip_runtime.h>
#include <hip/hip_bf16.h>
#include <math.h>

#define HID 64
#define NBA 512        // phase A/B blocks
#define NBUCK 256      // buckets (key>>9)
#define BSHIFT 9
#define BINS 512       // nodes per bucket
#define NBN (NBUCK * NBA)   // 131072 counters per side

typedef __attribute__((ext_vector_type(8))) short bf16x8;
typedef __attribute__((ext_vector_type(4))) float f32x4;

// ---- bf16 pack/unpack (RNE) ----
__device__ __forceinline__ unsigned int bf16r(float f) {
    unsigned int u = __float_as_uint(f);
    return (u + 0x7fffu + ((u >> 16) & 1u)) >> 16;
}
__device__ __forceinline__ unsigned int pack2(float a, float b) {
    return bf16r(a) | (bf16r(b) << 16);
}
__device__ __forceinline__ float lo2f(unsigned int u) { return __uint_as_float(u << 16); }
__device__ __forceinline__ float hi2f(unsigned int u) { return __uint_as_float(u & 0xffff0000u); }

__device__ __forceinline__ bf16x8 asbf(uint4 u) {
    union { uint4 u4; bf16x8 b; } c; c.u4 = u; return c.b;
}
__device__ __forceinline__ void load8(const float* p, float* d) {
    float4 a = *(const float4*)p, b = *(const float4*)(p + 4);
    d[0]=a.x; d[1]=a.y; d[2]=a.z; d[3]=a.w; d[4]=b.x; d[5]=b.y; d[6]=b.z; d[7]=b.w;
}

// ---------------- phase A: per-block bucket counts (LDS only) ----------------
__global__ void bucketA_kernel(const int* __restrict__ ei, int E,
                               int* __restrict__ cntsc) {
    __shared__ int cd[NBUCK], cs[NBUCK];
    int t = threadIdx.x;
    cd[t] = 0; cs[t] = 0;
    __syncthreads();
    int ce = (E + NBA - 1) / NBA;
    int e0 = blockIdx.x * ce, e1 = min(e0 + ce, E);
    for (int e = e0 + t; e < e1; e += 256) {
        int s = ei[e], d = ei[E + e];
        atomicAdd(&cs[s >> BSHIFT], 1);
        atomicAdd(&cd[d >> BSHIFT], 1);
    }
    __syncthreads();
    cntsc[t * NBA + blockIdx.x]       = cd[t];   // dst side [0, NBN)
    cntsc[NBN + t * NBA + blockIdx.x] = cs[t];   // src side [NBN, 2*NBN)
}

// ---------------- 3-kernel exclusive scan (generic, n = 2*NBN) ---------------
__global__ void scanA_kernel(const int* __restrict__ cnt, int* __restrict__ bs, int N) {
    __shared__ int s[256];
    int t = threadIdx.x, n = blockIdx.x * 256 + t;
    s[t] = (n < N) ? cnt[n] : 0;
    __syncthreads();
    for (int off = 128; off > 0; off >>= 1) {
        if (t < off) s[t] += s[t + off];
        __syncthreads();
    }
    if (t == 0) bs[blockIdx.x] = s[0];
}

__global__ void scanB_kernel(int* __restrict__ bs, int nb) {
    __shared__ int s[1024];
    int t = threadIdx.x;
    int orig = (t < nb) ? bs[t] : 0;
    s[t] = orig;
    __syncthreads();
    for (int off = 1; off < 1024; off <<= 1) {
        int v = (t >= off) ? s[t - off] : 0;
        __syncthreads();
        s[t] += v;
        __syncthreads();
    }
    if (t < nb) bs[t] = s[t] - orig;   // exclusive
}

__global__ void scanC_kernel(const int* __restrict__ cnt, const int* __restrict__ bs,
                             int* __restrict__ outp, int N) {
    __shared__ int s[256];
    int t = threadIdx.x, n = blockIdx.x * 256 + t;
    int c = (n < N) ? cnt[n] : 0;
    s[t] = c;
    __syncthreads();
    for (int off = 1; off < 256; off <<= 1) {
        int v = (t >= off) ? s[t - off] : 0;
        __syncthreads();
        s[t] += v;
        __syncthreads();
    }
    if (n < N) outp[n] = bs[blockIdx.x] + s[t] - c;
}

// ---------------- phase B: scatter packed records into bucket regions --------
// dstrec u32 = src | (dstbin << 17)   (src < 2^17, bin 9 bits)
__global__ void bucketB_kernel(const int* __restrict__ ei, int E,
                               const int* __restrict__ scanned,
                               unsigned int* __restrict__ dstrec,
                               int* __restrict__ srckeys) {
    __shared__ int cd[NBUCK], cs[NBUCK], bd[NBUCK], bsr[NBUCK];
    int t = threadIdx.x;
    cd[t] = 0; cs[t] = 0;
    bd[t]  = scanned[t * NBA + blockIdx.x];
    bsr[t] = scanned[NBN + t * NBA + blockIdx.x] - E;
    __syncthreads();
    int ce = (E + NBA - 1) / NBA;
    int e0 = blockIdx.x * ce, e1 = min(e0 + ce, E);
    for (int e = e0 + t; e < e1; e += 256) {
        int s = ei[e], d = ei[E + e];
        int db = d >> BSHIFT, sb = s >> BSHIFT;
        int rd = atomicAdd(&cd[db], 1);
        dstrec[bd[db] + rd] = (unsigned int)s | ((unsigned int)(d & (BINS - 1)) << 17);
        int rs = atomicAdd(&cs[sb], 1);
        srckeys[bsr[sb] + rs] = s;
    }
}

// ---------------- phase C2: per-bucket src counts -> dinv --------------------
__global__ void bucketC2_kernel(const int* __restrict__ srckeys,
                                const int* __restrict__ scanned,
                                float* __restrict__ dinv, int N, int E) {
    __shared__ int deg[BINS];
    int b = blockIdx.x, t = threadIdx.x;   // 512 threads
    deg[t] = 0;
    __syncthreads();
    int start = scanned[NBN + b * NBA] - E;
    int end   = (b < NBUCK - 1) ? scanned[NBN + (b + 1) * NBA] - E : E;
    for (int i = start + t; i < end; i += BINS)
        atomicAdd(&deg[srckeys[i] & (BINS - 1)], 1);
    __syncthreads();
    int node = (b << BSHIFT) + t;
    if (node < N) {
        int dg = deg[t];
        dinv[node] = dg > 0 ? rsqrtf((float)dg) : 0.0f;
    }
}

// ---------------- phase C1: per-bucket CSR (row, cnt, srcw) ------------------
__global__ void bucketC1_kernel(const unsigned int* __restrict__ dstrec,
                                const int* __restrict__ scanned,
                                const float* __restrict__ dinv,
                                int* __restrict__ row, int* __restrict__ cnt,
                                int2* __restrict__ srcw, int N, int E) {
    __shared__ int lc[BINS], ls[BINS], lr[BINS];
    int b = blockIdx.x, t = threadIdx.x;   // 512 threads
    lc[t] = 0; lr[t] = 0;
    __syncthreads();
    int start = scanned[b * NBA];
    int end   = (b < NBUCK - 1) ? scanned[(b + 1) * NBA] : E;
    for (int i = start + t; i < end; i += BINS)
        atomicAdd(&lc[dstrec[i] >> 17], 1);
    __syncthreads();
    // inclusive scan of lc (Hillis-Steele, 512 threads)
    ls[t] = lc[t];
    __syncthreads();
    for (int off = 1; off < BINS; off <<= 1) {
        int v = (t >= off) ? ls[t - off] : 0;
        __syncthreads();
        ls[t] += v;
        __syncthreads();
    }
    int rl = start + ls[t] - lc[t];   // exclusive -> global row
    int node = (b << BSHIFT) + t;
    if (node < N) { row[node] = rl; cnt[node] = lc[t]; }
    __syncthreads();
    ls[t] = rl;                        // reuse as scatter base
    __syncthreads();
    for (int i = start + t; i < end; i += BINS) {
        unsigned int rec = dstrec[i];
        int bin = (int)(rec >> 17);
        int src = (int)(rec & 0x1FFFFu);
        int p = ls[bin] + atomicAdd(&lr[bin], 1);
        srcw[p] = make_int2(src, __float_as_int(dinv[src]));
    }
}

// ---------------- pack transposed bf16 weight tables -------------------------
__global__ void packwT_kernel(const float* __restrict__ W2, const float* __restrict__ Wz,
                              const float* __restrict__ Wr, const float* __restrict__ Wc,
                              unsigned int* __restrict__ WT) {
    int idx = blockIdx.x * blockDim.x + threadIdx.x;
    if (idx >= 18432) return;
    float v0, v1;
    if (idx < 6144) {
        int c = idx / 96, kk = idx % 96;
        int k0 = 2 * kk;
        if (k0 < 64) {
            v0 = W2[k0 * 64 + c] - W2[8192 + k0 * 64 + c];
            v1 = W2[(k0 + 1) * 64 + c] - W2[8192 + (k0 + 1) * 64 + c];
        } else if (k0 < 128) {
            v0 = W2[4096 + (k0 - 64) * 64 + c];
            v1 = W2[4096 + (k0 - 63) * 64 + c];
        } else {
            v0 = 2.0f * W2[8192 + (k0 - 128) * 64 + c];
            v1 = 2.0f * W2[8192 + (k0 - 127) * 64 + c];
        }
    } else if (idx < 14336) {
        int t = idx - 6144;
        int c = t / 64, kk = t % 64, k0 = 2 * kk;
        const float* Ws = (c < 64) ? Wz : Wr;
        int cc = c & 63;
        v0 = Ws[k0 * 64 + cc];
        v1 = Ws[(k0 + 1) * 64 + cc];
    } else {
        int t = idx - 14336;
        int c = t / 64, kk = t % 64, k0 = 2 * kk;
        v0 = Wc[k0 * 64 + c];
        v1 = Wc[(k0 + 1) * 64 + c];
    }
    WT[idx] = pack2(v0, v1);
}

// ---------------- pack h (fp32) -> monolithic bf16x2 table (32 u32/row) ------
__global__ void packh_kernel(const float* __restrict__ h, unsigned int* __restrict__ hbf,
                             int total2) {
    int i = blockIdx.x * blockDim.x + threadIdx.x;
    if (i < total2) {
        float2 v = ((const float2*)h)[i];
        hbf[i] = pack2(v.x, v.y);
    }
}

#define FMA8(ww, vv, xvv) \
    a0 = fmaf(ww, lo2f(vv.x), a0); a1 = fmaf(ww, hi2f(vv.x), a1); \
    a2 = fmaf(ww, lo2f(vv.y), a2); a3 = fmaf(ww, hi2f(vv.y), a3); \
    a4 = fmaf(ww, lo2f(vv.z), a4); a5 = fmaf(ww, hi2f(vv.z), a5); \
    a6 = fmaf(ww, lo2f(vv.w), a6); a7 = fmaf(ww, hi2f(vv.w), a7); \
    ax0 = fmaf(ww, xvv.x, ax0);    ax1 = fmaf(ww, xvv.y, ax1);

// ---------------- fused 64ch-bf16 + 2ch-fp32 gather propagation --------------
// wave per node; 8 edge slots x 8 lanes. 128-B aligned channel rows (2 cache
// lines); x-pairs in a separate 800KB L2-resident array. Wave-uniform branch:
// k<=16 single shot (2 edges/group), else 4-deep loop.
__global__ void gather64_kernel(const int* __restrict__ row, const int* __restrict__ cnt,
                                const int2* __restrict__ srcw, const float* __restrict__ dinv,
                                const unsigned int* __restrict__ src,   // 32 u32/row
                                const float2* __restrict__ xsrc,        // [N]
                                unsigned int* __restrict__ dst,
                                float2* __restrict__ xdst, int N) {
    int wu = __builtin_amdgcn_readfirstlane((int)threadIdx.x >> 6);
    int n = blockIdx.x * 4 + wu;
    if (n >= N) return;
    int lane = threadIdx.x & 63;
    int t    = lane & 7;      // u32 quad within row (channels 8t..8t+7)
    int slot = lane >> 3;     // edge slot 0..7
    int start = row[n], k = cnt[n];
    float a0 = 0, a1 = 0, a2 = 0, a3 = 0, a4 = 0, a5 = 0, a6 = 0, a7 = 0;
    float ax0 = 0, ax1 = 0;
    if (k <= 16) {
        if (slot < k) {
            int2 rec0 = srcw[start + slot];
            bool h1 = slot + 8 < k;
            int2 rec1 = h1 ? srcw[start + slot + 8] : rec0;
            uint4 v0 = ((const uint4*)(src + (size_t)rec0.x * 32))[t];
            uint4 v1 = ((const uint4*)(src + (size_t)rec1.x * 32))[t];
            float2 xv0 = xsrc[rec0.x];
            float2 xv1 = xsrc[rec1.x];
            float w0 = __int_as_float(rec0.y);
            float w1 = h1 ? __int_as_float(rec1.y) : 0.0f;
            FMA8(w0, v0, xv0)
            FMA8(w1, v1, xv1)
        }
    } else {
        for (int e = slot; e < k; e += 32) {   // 4 edges in flight per group
            int2 rec0 = srcw[start + e];
            bool h1 = (e + 8) < k, h2 = (e + 16) < k, h3 = (e + 24) < k;
            int2 rec1 = h1 ? srcw[start + e + 8]  : rec0;
            int2 rec2 = h2 ? srcw[start + e + 16] : rec0;
            int2 rec3 = h3 ? srcw[start + e + 24] : rec0;
            uint4 v0 = ((const uint4*)(src + (size_t)rec0.x * 32))[t];
            uint4 v1 = ((const uint4*)(src + (size_t)rec1.x * 32))[t];
            uint4 v2 = ((const uint4*)(src + (size_t)rec2.x * 32))[t];
            uint4 v3 = ((const uint4*)(src + (size_t)rec3.x * 32))[t];
            float2 xv0 = xsrc[rec0.x];
            float2 xv1 = xsrc[rec1.x];
            float2 xv2 = xsrc[rec2.x];
            float2 xv3 = xsrc[rec3.x];
            float w0 = __int_as_float(rec0.y);
            float w1 = h1 ? __int_as_float(rec1.y) : 0.0f;
            float w2 = h2 ? __int_as_float(rec2.y) : 0.0f;
            float w3 = h3 ? __int_as_float(rec3.y) : 0.0f;
            FMA8(w0, v0, xv0)
            FMA8(w1, v1, xv1)
            FMA8(w2, v2, xv2)
            FMA8(w3, v3, xv3)
        }
    }
    a0 += __shfl_xor(a0, 8);  a1 += __shfl_xor(a1, 8);
    a2 += __shfl_xor(a2, 8);  a3 += __shfl_xor(a3, 8);
    a4 += __shfl_xor(a4, 8);  a5 += __shfl_xor(a5, 8);
    a6 += __shfl_xor(a6, 8);  a7 += __shfl_xor(a7, 8);
    ax0 += __shfl_xor(ax0, 8);  ax1 += __shfl_xor(ax1, 8);
    a0 += __shfl_xor(a0, 16); a1 += __shfl_xor(a1, 16);
    a2 += __shfl_xor(a2, 16); a3 += __shfl_xor(a3, 16);
    a4 += __shfl_xor(a4, 16); a5 += __shfl_xor(a5, 16);
    a6 += __shfl_xor(a6, 16); a7 += __shfl_xor(a7, 16);
    ax0 += __shfl_xor(ax0, 16); ax1 += __shfl_xor(ax1, 16);
    a0 += __shfl_xor(a0, 32); a1 += __shfl_xor(a1, 32);
    a2 += __shfl_xor(a2, 32); a3 += __shfl_xor(a3, 32);
    a4 += __shfl_xor(a4, 32); a5 += __shfl_xor(a5, 32);
    a6 += __shfl_xor(a6, 32); a7 += __shfl_xor(a7, 32);
    ax0 += __shfl_xor(ax0, 32); ax1 += __shfl_xor(ax1, 32);
    if (slot == 0) {
        float dn = -dinv[n];
        unsigned int* drow = dst + (size_t)n * 32;
        uint4 o;
        o.x = pack2(dn * a0, dn * a1);
        o.y = pack2(dn * a2, dn * a3);
        o.z = pack2(dn * a4, dn * a5);
        o.w = pack2(dn * a6, dn * a7);
        ((uint4*)drow)[t] = o;
        if (t == 0)
            xdst[n] = make_float2(dn * ax0, dn * ax1);
    }
}

// ---------------- MFMA fused input_conv + hidden_conv + GRU gates -----------
// Block = 4 waves (128 nodes), wave = 32 nodes (mt=2 ILP). WzrT+WcT staged in
// LDS per block (padded row stride 68 u32 -> <=2-way banks). Proven round-14.
__global__ __launch_bounds__(256, 2) void gate_mfma_kernel(
    float* __restrict__ out,
    const float* __restrict__ x,
    const float* __restrict__ h,
    const float* __restrict__ txa,
    const float* __restrict__ txb,
    const unsigned int* __restrict__ t1u,   // bf16 rows: prop(h)
    const unsigned int* __restrict__ ppu,   // bf16 rows: prop(prop(h))
    const float* __restrict__ W1, const float* __restrict__ b1,
    const unsigned int* __restrict__ WT,
    const float* __restrict__ b2, const float* __restrict__ bz,
    const float* __restrict__ br, const float* __restrict__ bc,
    int N) {
    __shared__ __align__(16) unsigned int s_wzr[128 * 68];   // 34816 B
    __shared__ __align__(16) unsigned int s_wc [64 * 68];    // 17408 B
    __shared__ unsigned short tr[4][32][72];                 // 18432 B

    int tid  = threadIdx.x;
    int lane = tid & 63;
    int wu   = __builtin_amdgcn_readfirstlane(tid >> 6);
    int q    = lane >> 4;      // 0..3
    int r16  = lane & 15;
    int base = blockIdx.x * 128 + wu * 32;

    int nA[2];
    nA[0] = min(base + r16, N - 1);
    nA[1] = min(base + 16 + r16, N - 1);

    const unsigned int* W2eT = WT;

    // ---- stage WzrT (8192 u32) + WcT (4096 u32) into padded LDS ----
    {
        const uint4* wzr4 = (const uint4*)(WT + 6144);
        const uint4* wc4  = (const uint4*)(WT + 14336);
        #pragma unroll
        for (int i = 0; i < 8; ++i) {
            int idx4 = tid + i * 256;            // 0..2047 uint4
            uint4 v = wzr4[idx4];
            int r = idx4 >> 4, c4 = (idx4 & 15) * 4;
            *(uint4*)&s_wzr[r * 68 + c4] = v;
        }
        #pragma unroll
        for (int i = 0; i < 4; ++i) {
            int idx4 = tid + i * 256;            // 0..1023 uint4
            uint4 v = wc4[idx4];
            int r = idx4 >> 4, c4 = (idx4 & 15) * 4;
            *(uint4*)&s_wc[r * 68 + c4] = v;
        }
    }

    // ---- ic A-fragments (computed in frag layout on VALU) ----
    uint4 icA[2][2];
    {
        float2 xv[2], tav[2], tbv[2];
        #pragma unroll
        for (int mt = 0; mt < 2; ++mt) {
            xv[mt]  = ((const float2*)x)[nA[mt]];
            tav[mt] = ((const float2*)txa)[nA[mt]];
            tbv[mt] = ((const float2*)txb)[nA[mt]];
        }
        #pragma unroll
        for (int kf = 0; kf < 2; ++kf) {
            int ch0 = kf * 32 + 8 * q;
            float b1s[8], w0[8], w1s[8], w2[8], w3[8], w4[8], w5[8];
            load8(b1 + ch0, b1s);
            load8(W1 + ch0, w0);       load8(W1 + 64 + ch0, w1s);
            load8(W1 + 128 + ch0, w2); load8(W1 + 192 + ch0, w3);
            load8(W1 + 256 + ch0, w4); load8(W1 + 320 + ch0, w5);
            #pragma unroll
            for (int mt = 0; mt < 2; ++mt) {
                float t20 = 2.0f * tbv[mt].x - xv[mt].x;
                float t21 = 2.0f * tbv[mt].y - xv[mt].y;
                unsigned int pr[4];
                #pragma unroll
                for (int p = 0; p < 4; ++p) {
                    float v0 = b1s[2*p]   + xv[mt].x * w0[2*p]   + xv[mt].y * w1s[2*p]
                             + tav[mt].x * w2[2*p]   + tav[mt].y * w3[2*p]
                             + t20 * w4[2*p]   + t21 * w5[2*p];
                    float v1 = b1s[2*p+1] + xv[mt].x * w0[2*p+1] + xv[mt].y * w1s[2*p+1]
                             + tav[mt].x * w2[2*p+1] + tav[mt].y * w3[2*p+1]
                             + t20 * w4[2*p+1] + t21 * w5[2*p+1];
                    pr[p] = pack2(v0, v1);
                }
                icA[mt][kf] = make_uint4(pr[0], pr[1], pr[2], pr[3]);
            }
        }
    }

    // ---- GEMM1: hc = [h|t1|pp] @ W2eff  (K=192, 6 k-steps; B from global) ----
    f32x4 acc1[2][4];
    #pragma unroll
    for (int mt = 0; mt < 2; ++mt)
        #pragma unroll
        for (int nt = 0; nt < 4; ++nt)
            acc1[mt][nt] = (f32x4){0.0f, 0.0f, 0.0f, 0.0f};

    #pragma unroll
    for (int ks = 0; ks < 6; ++ks) {
        bf16x8 a[2];
        if (ks < 2) {
            #pragma unroll
            for (int mt = 0; mt < 2; ++mt) {
                float hs[8];
                load8(h + (size_t)nA[mt] * 64 + ks * 32 + 8 * q, hs);
                uint4 u;
                u.x = pack2(hs[0], hs[1]); u.y = pack2(hs[2], hs[3]);
                u.z = pack2(hs[4], hs[5]); u.w = pack2(hs[6], hs[7]);
                a[mt] = asbf(u);
            }
        } else {
            const unsigned int* tab = (ks < 4) ? t1u : ppu;
            int ksl = ks & 1;
            #pragma unroll
            for (int mt = 0; mt < 2; ++mt)
                a[mt] = asbf(*(const uint4*)(tab + (size_t)nA[mt] * 32 + ksl * 16 + q * 4));
        }
        #pragma unroll
        for (int nt = 0; nt < 4; ++nt) {
            bf16x8 b = asbf(*(const uint4*)(W2eT + (nt * 16 + r16) * 96 + ks * 16 + q * 4));
            #pragma unroll
            for (int mt = 0; mt < 2; ++mt)
                acc1[mt][nt] = __builtin_amdgcn_mfma_f32_16x16x32_bf16(a[mt], b, acc1[mt][nt], 0, 0, 0);
        }
    }

    __syncthreads();   // staged weights ready (overlapped with icA + GEMM1)

    // ---- add b2; per-wave LDS transpose hc -> A-frag layout ----
    float b2v[4];
    #pragma unroll
    for (int nt = 0; nt < 4; ++nt) b2v[nt] = b2[nt * 16 + r16];
    #pragma unroll
    for (int mt = 0; mt < 2; ++mt)
        #pragma unroll
        for (int nt = 0; nt < 4; ++nt)
            #pragma unroll
            for (int reg = 0; reg < 4; ++reg) {
                acc1[mt][nt][reg] += b2v[nt];
                tr[wu][mt * 16 + 4 * q + reg][nt * 16 + r16] =
                    (unsigned short)bf16r(acc1[mt][nt][reg]);
            }
    __builtin_amdgcn_wave_barrier();
    bf16x8 hcA[2][2];
    #pragma unroll
    for (int mt = 0; mt < 2; ++mt)
        #pragma unroll
        for (int kf = 0; kf < 2; ++kf)
            hcA[mt][kf] = asbf(*(const uint4*)&tr[wu][mt * 16 + r16][kf * 32 + 8 * q]);
    __builtin_amdgcn_wave_barrier();

    // ---- GEMM2: [z|r] = [ic|hc] @ [Wz|Wr]  (K=128, N=128; B from LDS) ----
    f32x4 acc2[2][8];
    #pragma unroll
    for (int mt = 0; mt < 2; ++mt)
        #pragma unroll
        for (int nt = 0; nt < 8; ++nt)
            acc2[mt][nt] = (f32x4){0.0f, 0.0f, 0.0f, 0.0f};

    #pragma unroll
    for (int kf = 0; kf < 4; ++kf) {
        bf16x8 a[2];
        a[0] = (kf < 2) ? asbf(icA[0][kf]) : hcA[0][kf - 2];
        a[1] = (kf < 2) ? asbf(icA[1][kf]) : hcA[1][kf - 2];
        #pragma unroll
        for (int nt = 0; nt < 8; ++nt) {
            bf16x8 b = asbf(*(const uint4*)&s_wzr[(nt * 16 + r16) * 68 + kf * 16 + q * 4]);
            #pragma unroll
            for (int mt = 0; mt < 2; ++mt)
                acc2[mt][nt] = __builtin_amdgcn_mfma_f32_16x16x32_bf16(a[mt], b, acc2[mt][nt], 0, 0, 0);
        }
    }

    // ---- gates: z = sig(az), r = sig(ar); transpose r*hc ----
    float bzv[4], brv[4];
    #pragma unroll
    for (int nt = 0; nt < 4; ++nt) { bzv[nt] = bz[nt * 16 + r16]; brv[nt] = br[nt * 16 + r16]; }
    float zz[2][4][4];
    #pragma unroll
    for (int mt = 0; mt < 2; ++mt)
        #pragma unroll
        for (int nt = 0; nt < 4; ++nt)
            #pragma unroll
            for (int reg = 0; reg < 4; ++reg) {
                zz[mt][nt][reg] = 1.0f / (1.0f + __expf(-(acc2[mt][nt][reg] + bzv[nt])));
                float rr = 1.0f / (1.0f + __expf(-(acc2[mt][nt + 4][reg] + brv[nt])));
                float rhc = rr * acc1[mt][nt][reg];
                tr[wu][mt * 16 + 4 * q + reg][nt * 16 + r16] = (unsigned short)bf16r(rhc);
            }
    __builtin_amdgcn_wave_barrier();
    bf16x8 rhcA[2][2];
    #pragma unroll
    for (int mt = 0; mt < 2; ++mt)
        #pragma unroll
        for (int kf = 0; kf < 2; ++kf)
            rhcA[mt][kf] = asbf(*(const uint4*)&tr[wu][mt * 16 + r16][kf * 32 + 8 * q]);
    __builtin_amdgcn_wave_barrier();

    // ---- GEMM3: cand = [ic|r*hc] @ Wc  (K=128, N=64; B from LDS) ----
    f32x4 acc3[2][4];
    #pragma unroll
    for (int mt = 0; mt < 2; ++mt)
        #pragma unroll
        for (int nt = 0; nt < 4; ++nt)
            acc3[mt][nt] = (f32x4){0.0f, 0.0f, 0.0f, 0.0f};

    #pragma unroll
    for (int kf = 0; kf < 4; ++kf) {
        bf16x8 a[2];
        a[0] = (kf < 2) ? asbf(icA[0][kf]) : rhcA[0][kf - 2];
        a[1] = (kf < 2) ? asbf(icA[1][kf]) : rhcA[1][kf - 2];
        #pragma unroll
        for (int nt = 0; nt < 4; ++nt) {
            bf16x8 b = asbf(*(const uint4*)&s_wc[(nt * 16 + r16) * 68 + kf * 16 + q * 4]);
            #pragma unroll
            for (int mt = 0; mt < 2; ++mt)
                acc3[mt][nt] = __builtin_amdgcn_mfma_f32_16x16x32_bf16(a[mt], b, acc3[mt][nt], 0, 0, 0);
        }
    }

    // ---- epilogue: out = z*h + (1-z)*tanh(cand + bc) ----
    float bcv[4];
    #pragma unroll
    for (int nt = 0; nt < 4; ++nt) bcv[nt] = bc[nt * 16 + r16];
    #pragma unroll
    for (int mt = 0; mt < 2; ++mt)
        #pragma unroll
        for (int nt = 0; nt < 4; ++nt)
            #pragma unroll
            for (int reg = 0; reg < 4; ++reg) {
                int node = base + mt * 16 + 4 * q + reg;
                if (node < N) {
                    float a = acc3[mt][nt][reg] + bcv[nt];
                    a = fminf(fmaxf(a, -40.0f), 40.0f);
                    float e = __expf(2.0f * a);
                    float ht = 1.0f - 2.0f / (e + 1.0f);
                    float hv = h[(size_t)node * 64 + nt * 16 + r16];
                    float z = zz[mt][nt][reg];
                    out[(size_t)node * 64 + nt * 16 + r16] = z * hv + (1.0f - z) * ht;
                }
            }
}

extern "C" void kernel_launch(void* const* d_in, const int* in_sizes, int n_in,
                              void* d_out, int out_size, void* d_ws, size_t ws_size,
                              hipStream_t stream) {
    const float* x  = (const float*)d_in[0];
    const int*   ei = (const int*)  d_in[1];
    const float* h  = (const float*)d_in[2];
    const float* W1 = (const float*)d_in[3];
    const float* b1 = (const float*)d_in[4];
    const float* W2 = (const float*)d_in[5];
    const float* b2 = (const float*)d_in[6];
    const float* Wz = (const float*)d_in[7];
    const float* bz = (const float*)d_in[8];
    const float* Wr = (const float*)d_in[9];
    const float* br = (const float*)d_in[10];
    const float* Wc = (const float*)d_in[11];
    const float* bc = (const float*)d_in[12];
    float* out = (float*)d_out;

    int N = in_sizes[0] / 2;     // 100000
    int E = in_sizes[1] / 2;     // 1600000

    // workspace layout (u32 units):
    //   dinv N | row N | cnt N | txa 2N | txb 2N | bs 1024 | WT 18432
    //   | cntsc 2*NBN | scanned 2*NBN | srcw 2E
    //   O (64-B aligned): bufA 32N | hpp 32N
    //   build temps alias bufA span: dstrec E | srckeys E  (= 2E = 32N exactly)
    char* wsb = (char*)d_ws;
    float* dinv = (float*)wsb;                                   // N
    int*   row  = (int*)  (wsb + (size_t)N * 4);                 // N
    int*   cnt  = (int*)  (wsb + (size_t)2 * N * 4);             // N
    float* txa  = (float*)(wsb + (size_t)3 * N * 4);             // 2N
    float* txb  = (float*)(wsb + (size_t)5 * N * 4);             // 2N
    int*   bs   = (int*)  (wsb + (size_t)7 * N * 4);             // 1024
    unsigned int* WT = (unsigned int*)(wsb + ((size_t)7 * N + 1024) * 4);      // 18432
    int*   cntsc   = (int*)(wsb + ((size_t)7 * N + 19456) * 4);                // 2*NBN
    int*   scanned = (int*)(wsb + ((size_t)7 * N + 19456 + 2 * NBN) * 4);      // 2*NBN
    int2*  srcw = (int2*)(wsb + ((size_t)7 * N + 19456 + 4 * NBN) * 4);        // 2E
    size_t O = (size_t)7 * N + 19456 + 4 * (size_t)NBN + 2 * (size_t)E;
    unsigned int* bufA = (unsigned int*)(wsb + O * 4);                         // 32N
    unsigned int* hpp  = (unsigned int*)(wsb + (O + (size_t)32 * N) * 4);      // 32N
    unsigned int* dstrec = (unsigned int*)(wsb + O * 4);                       // E (alias)
    int* srckeys = (int*)(wsb + (O + (size_t)E) * 4);                          // E (alias)

    // ---- bucketed CSR build (no global atomics, no memset) ----
    bucketA_kernel<<<NBA, 256, 0, stream>>>(ei, E, cntsc);
    int scn = 2 * NBN;
    scanA_kernel<<<scn / 256, 256, 0, stream>>>(cntsc, bs, scn);
    scanB_kernel<<<1, 1024, 0, stream>>>(bs, scn / 256);
    scanC_kernel<<<scn / 256, 256, 0, stream>>>(cntsc, bs, scanned, scn);
    bucketB_kernel<<<NBA, 256, 0, stream>>>(ei, E, scanned, dstrec, srckeys);
    bucketC2_kernel<<<NBUCK, BINS, 0, stream>>>(srckeys, scanned, dinv, N, E);
    bucketC1_kernel<<<NBUCK, BINS, 0, stream>>>(dstrec, scanned, dinv, row, cnt, srcw, N, E);

    // packs (hpp does not overlap build temps; bufA reused only after C1)
    packwT_kernel<<<(18432 + 255) / 256, 256, 0, stream>>>(W2, Wz, Wr, Wc, WT);
    packh_kernel <<<(32 * N + 255) / 256, 256, 0, stream>>>(h, hpp, 32 * N);

    // fused hidden+input propagation: [hpp|x] -> [bufA|txa] -> [hpp|txb]
    int gblocks = (N + 3) / 4;
    gather64_kernel<<<gblocks, 256, 0, stream>>>(row, cnt, srcw, dinv, hpp,
                                                 (const float2*)x, bufA,
                                                 (float2*)txa, N);
    gather64_kernel<<<gblocks, 256, 0, stream>>>(row, cnt, srcw, dinv, bufA,
                                                 (const float2*)txa, hpp,
                                                 (float2*)txb, N);

    // fused MFMA gate (4 waves/block, 128 nodes; WzrT/WcT staged in LDS)
    int gateblocks = (N + 127) / 128;
    gate_mfma_kernel<<<gateblocks, 256, 0, stream>>>(
        out, x, h, txa, txb, bufA, hpp, W1, b1, WT, b2, bz, br, bc, N);
}

// Round 19
// 203.864 us; speedup vs baseline: 1.1449x; 1.0588x over previous
//
#include <hip/hip_runtime.h>
#include <hip/hip_bf16.h>
#include <math.h>

#define HID 64
#define NBA 512        // phase A/B blocks
#define NBUCK 256      // buckets (key>>9)
#define BSHIFT 9
#define BINS 512       // nodes per bucket
#define NBN (NBUCK * NBA)   // 131072 counters per side

typedef __attribute__((ext_vector_type(8))) short bf16x8;
typedef __attribute__((ext_vector_type(4))) float f32x4;

// ---- bf16 pack/unpack (RNE) ----
__device__ __forceinline__ unsigned int bf16r(float f) {
    unsigned int u = __float_as_uint(f);
    return (u + 0x7fffu + ((u >> 16) & 1u)) >> 16;
}
__device__ __forceinline__ unsigned int pack2(float a, float b) {
    return bf16r(a) | (bf16r(b) << 16);
}
__device__ __forceinline__ float lo2f(unsigned int u) { return __uint_as_float(u << 16); }
__device__ __forceinline__ float hi2f(unsigned int u) { return __uint_as_float(u & 0xffff0000u); }

__device__ __forceinline__ bf16x8 asbf(uint4 u) {
    union { uint4 u4; bf16x8 b; } c; c.u4 = u; return c.b;
}
__device__ __forceinline__ void load8(const float* p, float* d) {
    float4 a = *(const float4*)p, b = *(const float4*)(p + 4);
    d[0]=a.x; d[1]=a.y; d[2]=a.z; d[3]=a.w; d[4]=b.x; d[5]=b.y; d[6]=b.z; d[7]=b.w;
}

// ---------------- phase A: per-block bucket counts (LDS only) ----------------
__global__ void bucketA_kernel(const int* __restrict__ ei, int E,
                               int* __restrict__ cntsc) {
    __shared__ int cd[NBUCK], cs[NBUCK];
    int t = threadIdx.x;
    cd[t] = 0; cs[t] = 0;
    __syncthreads();
    int ce = (E + NBA - 1) / NBA;
    int e0 = blockIdx.x * ce, e1 = min(e0 + ce, E);
    for (int e = e0 + t; e < e1; e += 256) {
        int s = ei[e], d = ei[E + e];
        atomicAdd(&cs[s >> BSHIFT], 1);
        atomicAdd(&cd[d >> BSHIFT], 1);
    }
    __syncthreads();
    cntsc[t * NBA + blockIdx.x]       = cd[t];   // dst side [0, NBN)
    cntsc[NBN + t * NBA + blockIdx.x] = cs[t];   // src side [NBN, 2*NBN)
}

// ---------------- 3-kernel exclusive scan (generic, n = 2*NBN) ---------------
__global__ void scanA_kernel(const int* __restrict__ cnt, int* __restrict__ bs, int N) {
    __shared__ int s[256];
    int t = threadIdx.x, n = blockIdx.x * 256 + t;
    s[t] = (n < N) ? cnt[n] : 0;
    __syncthreads();
    for (int off = 128; off > 0; off >>= 1) {
        if (t < off) s[t] += s[t + off];
        __syncthreads();
    }
    if (t == 0) bs[blockIdx.x] = s[0];
}

__global__ void scanB_kernel(int* __restrict__ bs, int nb) {
    __shared__ int s[1024];
    int t = threadIdx.x;
    int orig = (t < nb) ? bs[t] : 0;
    s[t] = orig;
    __syncthreads();
    for (int off = 1; off < 1024; off <<= 1) {
        int v = (t >= off) ? s[t - off] : 0;
        __syncthreads();
        s[t] += v;
        __syncthreads();
    }
    if (t < nb) bs[t] = s[t] - orig;   // exclusive
}

__global__ void scanC_kernel(const int* __restrict__ cnt, const int* __restrict__ bs,
                             int* __restrict__ outp, int N) {
    __shared__ int s[256];
    int t = threadIdx.x, n = blockIdx.x * 256 + t;
    int c = (n < N) ? cnt[n] : 0;
    s[t] = c;
    __syncthreads();
    for (int off = 1; off < 256; off <<= 1) {
        int v = (t >= off) ? s[t - off] : 0;
        __syncthreads();
        s[t] += v;
        __syncthreads();
    }
    if (n < N) outp[n] = bs[blockIdx.x] + s[t] - c;
}

// ---------------- phase B: scatter packed records into bucket regions --------
// dstrec u32 = src | (dstbin << 17)   (src < 2^17, bin 9 bits)
__global__ void bucketB_kernel(const int* __restrict__ ei, int E,
                               const int* __restrict__ scanned,
                               unsigned int* __restrict__ dstrec,
                               int* __restrict__ srckeys) {
    __shared__ int cd[NBUCK], cs[NBUCK], bd[NBUCK], bsr[NBUCK];
    int t = threadIdx.x;
    cd[t] = 0; cs[t] = 0;
    bd[t]  = scanned[t * NBA + blockIdx.x];
    bsr[t] = scanned[NBN + t * NBA + blockIdx.x] - E;
    __syncthreads();
    int ce = (E + NBA - 1) / NBA;
    int e0 = blockIdx.x * ce, e1 = min(e0 + ce, E);
    for (int e = e0 + t; e < e1; e += 256) {
        int s = ei[e], d = ei[E + e];
        int db = d >> BSHIFT, sb = s >> BSHIFT;
        int rd = atomicAdd(&cd[db], 1);
        dstrec[bd[db] + rd] = (unsigned int)s | ((unsigned int)(d & (BINS - 1)) << 17);
        int rs = atomicAdd(&cs[sb], 1);
        srckeys[bsr[sb] + rs] = s;
    }
}

// ---------------- phase C2: per-bucket src counts -> dinv --------------------
__global__ void bucketC2_kernel(const int* __restrict__ srckeys,
                                const int* __restrict__ scanned,
                                float* __restrict__ dinv, int N, int E) {
    __shared__ int deg[BINS];
    int b = blockIdx.x, t = threadIdx.x;   // 512 threads
    deg[t] = 0;
    __syncthreads();
    int start = scanned[NBN + b * NBA] - E;
    int end   = (b < NBUCK - 1) ? scanned[NBN + (b + 1) * NBA] - E : E;
    for (int i = start + t; i < end; i += BINS)
        atomicAdd(&deg[srckeys[i] & (BINS - 1)], 1);
    __syncthreads();
    int node = (b << BSHIFT) + t;
    if (node < N) {
        int dg = deg[t];
        dinv[node] = dg > 0 ? rsqrtf((float)dg) : 0.0f;
    }
}

// ---------------- phase C1: per-bucket CSR (row, cnt, srcu) ------------------
__global__ void bucketC1_kernel(const unsigned int* __restrict__ dstrec,
                                const int* __restrict__ scanned,
                                int* __restrict__ row, int* __restrict__ cnt,
                                unsigned int* __restrict__ srcu, int N, int E) {
    __shared__ int lc[BINS], ls[BINS], lr[BINS];
    int b = blockIdx.x, t = threadIdx.x;   // 512 threads
    lc[t] = 0; lr[t] = 0;
    __syncthreads();
    int start = scanned[b * NBA];
    int end   = (b < NBUCK - 1) ? scanned[(b + 1) * NBA] : E;
    for (int i = start + t; i < end; i += BINS)
        atomicAdd(&lc[dstrec[i] >> 17], 1);
    __syncthreads();
    // inclusive scan of lc (Hillis-Steele, 512 threads)
    ls[t] = lc[t];
    __syncthreads();
    for (int off = 1; off < BINS; off <<= 1) {
        int v = (t >= off) ? ls[t - off] : 0;
        __syncthreads();
        ls[t] += v;
        __syncthreads();
    }
    int rl = start + ls[t] - lc[t];   // exclusive -> global row
    int node = (b << BSHIFT) + t;
    if (node < N) { row[node] = rl; cnt[node] = lc[t]; }
    __syncthreads();
    ls[t] = rl;                        // reuse as scatter base
    __syncthreads();
    for (int i = start + t; i < end; i += BINS) {
        unsigned int rec = dstrec[i];
        int bin = (int)(rec >> 17);
        int p = ls[bin] + atomicAdd(&lr[bin], 1);
        srcu[p] = rec & 0x1FFFFu;
    }
}

// ---------------- pack transposed bf16 weight tables -------------------------
__global__ void packwT_kernel(const float* __restrict__ W2, const float* __restrict__ Wz,
                              const float* __restrict__ Wr, const float* __restrict__ Wc,
                              unsigned int* __restrict__ WT) {
    int idx = blockIdx.x * blockDim.x + threadIdx.x;
    if (idx >= 18432) return;
    float v0, v1;
    if (idx < 6144) {
        int c = idx / 96, kk = idx % 96;
        int k0 = 2 * kk;
        if (k0 < 64) {
            v0 = W2[k0 * 64 + c] - W2[8192 + k0 * 64 + c];
            v1 = W2[(k0 + 1) * 64 + c] - W2[8192 + (k0 + 1) * 64 + c];
        } else if (k0 < 128) {
            v0 = W2[4096 + (k0 - 64) * 64 + c];
            v1 = W2[4096 + (k0 - 63) * 64 + c];
        } else {
            v0 = 2.0f * W2[8192 + (k0 - 128) * 64 + c];
            v1 = 2.0f * W2[8192 + (k0 - 127) * 64 + c];
        }
    } else if (idx < 14336) {
        int t = idx - 6144;
        int c = t / 64, kk = t % 64, k0 = 2 * kk;
        const float* Ws = (c < 64) ? Wz : Wr;
        int cc = c & 63;
        v0 = Ws[k0 * 64 + cc];
        v1 = Ws[(k0 + 1) * 64 + cc];
    } else {
        int t = idx - 14336;
        int c = t / 64, kk = t % 64, k0 = 2 * kk;
        v0 = Wc[k0 * 64 + c];
        v1 = Wc[(k0 + 1) * 64 + c];
    }
    WT[idx] = pack2(v0, v1);
}

// ---------------- pack h (fp32) -> monolithic bf16x2 table (32 u32/row) ------
__global__ void packh_kernel(const float* __restrict__ h, unsigned int* __restrict__ hbf,
                             int total2) {
    int i = blockIdx.x * blockDim.x + threadIdx.x;
    if (i < total2) {
        float2 v = ((const float2*)h)[i];
        hbf[i] = pack2(v.x, v.y);
    }
}

#define FMA8(ww, vv, xvv) \
    a0 = fmaf(ww, lo2f(vv.x), a0); a1 = fmaf(ww, hi2f(vv.x), a1); \
    a2 = fmaf(ww, lo2f(vv.y), a2); a3 = fmaf(ww, hi2f(vv.y), a3); \
    a4 = fmaf(ww, lo2f(vv.z), a4); a5 = fmaf(ww, hi2f(vv.z), a5); \
    a6 = fmaf(ww, lo2f(vv.w), a6); a7 = fmaf(ww, hi2f(vv.w), a7); \
    ax0 = fmaf(ww, xvv.x, ax0);    ax1 = fmaf(ww, xvv.y, ax1);

// ---------------- fused 64ch-bf16 + 2ch-fp32 gather propagation --------------
// wave per node; 8 edge slots x 8 lanes. 128-B aligned channel rows; weights
// from L2-resident dinv[] (srcu is u32 ids only). Wave-uniform k-branch.
__global__ void gather64_kernel(const int* __restrict__ row, const int* __restrict__ cnt,
                                const unsigned int* __restrict__ srcu,
                                const float* __restrict__ dinv,
                                const unsigned int* __restrict__ src,   // 32 u32/row
                                const float2* __restrict__ xsrc,        // [N]
                                unsigned int* __restrict__ dst,
                                float2* __restrict__ xdst, int N) {
    int wu = __builtin_amdgcn_readfirstlane((int)threadIdx.x >> 6);
    int n = blockIdx.x * 4 + wu;
    if (n >= N) return;
    int lane = threadIdx.x & 63;
    int t    = lane & 7;      // u32 quad within row (channels 8t..8t+7)
    int slot = lane >> 3;     // edge slot 0..7
    int start = row[n], k = cnt[n];
    float a0 = 0, a1 = 0, a2 = 0, a3 = 0, a4 = 0, a5 = 0, a6 = 0, a7 = 0;
    float ax0 = 0, ax1 = 0;
    if (k <= 16) {
        if (slot < k) {
            unsigned int s0 = srcu[start + slot];
            bool h1 = slot + 8 < k;
            unsigned int s1 = h1 ? srcu[start + slot + 8] : s0;
            uint4 v0 = ((const uint4*)(src + (size_t)s0 * 32))[t];
            uint4 v1 = ((const uint4*)(src + (size_t)s1 * 32))[t];
            float2 xv0 = xsrc[s0];
            float2 xv1 = xsrc[s1];
            float w0 = dinv[s0];
            float w1 = h1 ? dinv[s1] : 0.0f;
            FMA8(w0, v0, xv0)
            FMA8(w1, v1, xv1)
        }
    } else {
        for (int e = slot; e < k; e += 32) {   // 4 edges in flight per group
            unsigned int s0 = srcu[start + e];
            bool h1 = (e + 8) < k, h2 = (e + 16) < k, h3 = (e + 24) < k;
            unsigned int s1 = h1 ? srcu[start + e + 8]  : s0;
            unsigned int s2 = h2 ? srcu[start + e + 16] : s0;
            unsigned int s3 = h3 ? srcu[start + e + 24] : s0;
            uint4 v0 = ((const uint4*)(src + (size_t)s0 * 32))[t];
            uint4 v1 = ((const uint4*)(src + (size_t)s1 * 32))[t];
            uint4 v2 = ((const uint4*)(src + (size_t)s2 * 32))[t];
            uint4 v3 = ((const uint4*)(src + (size_t)s3 * 32))[t];
            float2 xv0 = xsrc[s0];
            float2 xv1 = xsrc[s1];
            float2 xv2 = xsrc[s2];
            float2 xv3 = xsrc[s3];
            float w0 = dinv[s0];
            float w1 = h1 ? dinv[s1] : 0.0f;
            float w2 = h2 ? dinv[s2] : 0.0f;
            float w3 = h3 ? dinv[s3] : 0.0f;
            FMA8(w0, v0, xv0)
            FMA8(w1, v1, xv1)
            FMA8(w2, v2, xv2)
            FMA8(w3, v3, xv3)
        }
    }
    a0 += __shfl_xor(a0, 8);  a1 += __shfl_xor(a1, 8);
    a2 += __shfl_xor(a2, 8);  a3 += __shfl_xor(a3, 8);
    a4 += __shfl_xor(a4, 8);  a5 += __shfl_xor(a5, 8);
    a6 += __shfl_xor(a6, 8);  a7 += __shfl_xor(a7, 8);
    ax0 += __shfl_xor(ax0, 8);  ax1 += __shfl_xor(ax1, 8);
    a0 += __shfl_xor(a0, 16); a1 += __shfl_xor(a1, 16);
    a2 += __shfl_xor(a2, 16); a3 += __shfl_xor(a3, 16);
    a4 += __shfl_xor(a4, 16); a5 += __shfl_xor(a5, 16);
    a6 += __shfl_xor(a6, 16); a7 += __shfl_xor(a7, 16);
    ax0 += __shfl_xor(ax0, 16); ax1 += __shfl_xor(ax1, 16);
    a0 += __shfl_xor(a0, 32); a1 += __shfl_xor(a1, 32);
    a2 += __shfl_xor(a2, 32); a3 += __shfl_xor(a3, 32);
    a4 += __shfl_xor(a4, 32); a5 += __shfl_xor(a5, 32);
    a6 += __shfl_xor(a6, 32); a7 += __shfl_xor(a7, 32);
    ax0 += __shfl_xor(ax0, 32); ax1 += __shfl_xor(ax1, 32);
    if (slot == 0) {
        float dn = -dinv[n];
        unsigned int* drow = dst + (size_t)n * 32;
        uint4 o;
        o.x = pack2(dn * a0, dn * a1);
        o.y = pack2(dn * a2, dn * a3);
        o.z = pack2(dn * a4, dn * a5);
        o.w = pack2(dn * a6, dn * a7);
        ((uint4*)drow)[t] = o;
        if (t == 0)
            xdst[n] = make_float2(dn * ax0, dn * ax1);
    }
}

// ---------------- MFMA fused input_conv + hidden_conv + GRU gates -----------
// Block = 4 waves (128 nodes), wave = 32 nodes (mt=2 ILP). WzrT+WcT staged in
// LDS (padded stride 68 -> <=2-way banks). GEMM1 A-frags + epilogue h come
// from the packed bf16 hbf table (no fp32 h reads, no VALU repacking).
__global__ __launch_bounds__(256, 2) void gate_mfma_kernel(
    float* __restrict__ out,
    const float* __restrict__ x,
    const unsigned int* __restrict__ hbf,   // bf16 rows: h
    const float* __restrict__ txa,
    const float* __restrict__ txb,
    const unsigned int* __restrict__ t1u,   // bf16 rows: prop(h)
    const unsigned int* __restrict__ ppu,   // bf16 rows: prop(prop(h))
    const float* __restrict__ W1, const float* __restrict__ b1,
    const unsigned int* __restrict__ WT,
    const float* __restrict__ b2, const float* __restrict__ bz,
    const float* __restrict__ br, const float* __restrict__ bc,
    int N) {
    __shared__ __align__(16) unsigned int s_wzr[128 * 68];   // 34816 B
    __shared__ __align__(16) unsigned int s_wc [64 * 68];    // 17408 B
    __shared__ unsigned short tr[4][32][72];                 // 18432 B

    int tid  = threadIdx.x;
    int lane = tid & 63;
    int wu   = __builtin_amdgcn_readfirstlane(tid >> 6);
    int q    = lane >> 4;      // 0..3
    int r16  = lane & 15;
    int base = blockIdx.x * 128 + wu * 32;

    int nA[2];
    nA[0] = min(base + r16, N - 1);
    nA[1] = min(base + 16 + r16, N - 1);

    const unsigned int* W2eT = WT;

    // ---- stage WzrT (8192 u32) + WcT (4096 u32) into padded LDS ----
    {
        const uint4* wzr4 = (const uint4*)(WT + 6144);
        const uint4* wc4  = (const uint4*)(WT + 14336);
        #pragma unroll
        for (int i = 0; i < 8; ++i) {
            int idx4 = tid + i * 256;            // 0..2047 uint4
            uint4 v = wzr4[idx4];
            int r = idx4 >> 4, c4 = (idx4 & 15) * 4;
            *(uint4*)&s_wzr[r * 68 + c4] = v;
        }
        #pragma unroll
        for (int i = 0; i < 4; ++i) {
            int idx4 = tid + i * 256;            // 0..1023 uint4
            uint4 v = wc4[idx4];
            int r = idx4 >> 4, c4 = (idx4 & 15) * 4;
            *(uint4*)&s_wc[r * 68 + c4] = v;
        }
    }

    // ---- ic A-fragments (computed in frag layout on VALU) ----
    uint4 icA[2][2];
    {
        float2 xv[2], tav[2], tbv[2];
        #pragma unroll
        for (int mt = 0; mt < 2; ++mt) {
            xv[mt]  = ((const float2*)x)[nA[mt]];
            tav[mt] = ((const float2*)txa)[nA[mt]];
            tbv[mt] = ((const float2*)txb)[nA[mt]];
        }
        #pragma unroll
        for (int kf = 0; kf < 2; ++kf) {
            int ch0 = kf * 32 + 8 * q;
            float b1s[8], w0[8], w1s[8], w2[8], w3[8], w4[8], w5[8];
            load8(b1 + ch0, b1s);
            load8(W1 + ch0, w0);       load8(W1 + 64 + ch0, w1s);
            load8(W1 + 128 + ch0, w2); load8(W1 + 192 + ch0, w3);
            load8(W1 + 256 + ch0, w4); load8(W1 + 320 + ch0, w5);
            #pragma unroll
            for (int mt = 0; mt < 2; ++mt) {
                float t20 = 2.0f * tbv[mt].x - xv[mt].x;
                float t21 = 2.0f * tbv[mt].y - xv[mt].y;
                unsigned int pr[4];
                #pragma unroll
                for (int p = 0; p < 4; ++p) {
                    float v0 = b1s[2*p]   + xv[mt].x * w0[2*p]   + xv[mt].y * w1s[2*p]
                             + tav[mt].x * w2[2*p]   + tav[mt].y * w3[2*p]
                             + t20 * w4[2*p]   + t21 * w5[2*p];
                    float v1 = b1s[2*p+1] + xv[mt].x * w0[2*p+1] + xv[mt].y * w1s[2*p+1]
                             + tav[mt].x * w2[2*p+1] + tav[mt].y * w3[2*p+1]
                             + t20 * w4[2*p+1] + t21 * w5[2*p+1];
                    pr[p] = pack2(v0, v1);
                }
                icA[mt][kf] = make_uint4(pr[0], pr[1], pr[2], pr[3]);
            }
        }
    }

    // ---- GEMM1: hc = [h|t1|pp] @ W2eff  (K=192; A-frags all from bf16 tables) ----
    f32x4 acc1[2][4];
    #pragma unroll
    for (int mt = 0; mt < 2; ++mt)
        #pragma unroll
        for (int nt = 0; nt < 4; ++nt)
            acc1[mt][nt] = (f32x4){0.0f, 0.0f, 0.0f, 0.0f};

    #pragma unroll
    for (int ks = 0; ks < 6; ++ks) {
        const unsigned int* tab = (ks < 2) ? hbf : ((ks < 4) ? t1u : ppu);
        int ksl = ks & 1;
        bf16x8 a[2];
        #pragma unroll
        for (int mt = 0; mt < 2; ++mt)
            a[mt] = asbf(*(const uint4*)(tab + (size_t)nA[mt] * 32 + ksl * 16 + q * 4));
        #pragma unroll
        for (int nt = 0; nt < 4; ++nt) {
            bf16x8 b = asbf(*(const uint4*)(W2eT + (nt * 16 + r16) * 96 + ks * 16 + q * 4));
            #pragma unroll
            for (int mt = 0; mt < 2; ++mt)
                acc1[mt][nt] = __builtin_amdgcn_mfma_f32_16x16x32_bf16(a[mt], b, acc1[mt][nt], 0, 0, 0);
        }
    }

    __syncthreads();   // staged weights ready (overlapped with icA + GEMM1)

    // ---- add b2; per-wave LDS transpose hc -> A-frag layout ----
    float b2v[4];
    #pragma unroll
    for (int nt = 0; nt < 4; ++nt) b2v[nt] = b2[nt * 16 + r16];
    #pragma unroll
    for (int mt = 0; mt < 2; ++mt)
        #pragma unroll
        for (int nt = 0; nt < 4; ++nt)
            #pragma unroll
            for (int reg = 0; reg < 4; ++reg) {
                acc1[mt][nt][reg] += b2v[nt];
                tr[wu][mt * 16 + 4 * q + reg][nt * 16 + r16] =
                    (unsigned short)bf16r(acc1[mt][nt][reg]);
            }
    __builtin_amdgcn_wave_barrier();
    bf16x8 hcA[2][2];
    #pragma unroll
    for (int mt = 0; mt < 2; ++mt)
        #pragma unroll
        for (int kf = 0; kf < 2; ++kf)
            hcA[mt][kf] = asbf(*(const uint4*)&tr[wu][mt * 16 + r16][kf * 32 + 8 * q]);
    __builtin_amdgcn_wave_barrier();

    // ---- GEMM2: [z|r] = [ic|hc] @ [Wz|Wr]  (K=128, N=128; B from LDS) ----
    f32x4 acc2[2][8];
    #pragma unroll
    for (int mt = 0; mt < 2; ++mt)
        #pragma unroll
        for (int nt = 0; nt < 8; ++nt)
            acc2[mt][nt] = (f32x4){0.0f, 0.0f, 0.0f, 0.0f};

    #pragma unroll
    for (int kf = 0; kf < 4; ++kf) {
        bf16x8 a[2];
        a[0] = (kf < 2) ? asbf(icA[0][kf]) : hcA[0][kf - 2];
        a[1] = (kf < 2) ? asbf(icA[1][kf]) : hcA[1][kf - 2];
        #pragma unroll
        for (int nt = 0; nt < 8; ++nt) {
            bf16x8 b = asbf(*(const uint4*)&s_wzr[(nt * 16 + r16) * 68 + kf * 16 + q * 4]);
            #pragma unroll
            for (int mt = 0; mt < 2; ++mt)
                acc2[mt][nt] = __builtin_amdgcn_mfma_f32_16x16x32_bf16(a[mt], b, acc2[mt][nt], 0, 0, 0);
        }
    }

    // ---- gates: z = sig(az), r = sig(ar); transpose r*hc ----
    float bzv[4], brv[4];
    #pragma unroll
    for (int nt = 0; nt < 4; ++nt) { bzv[nt] = bz[nt * 16 + r16]; brv[nt] = br[nt * 16 + r16]; }
    float zz[2][4][4];
    #pragma unroll
    for (int mt = 0; mt < 2; ++mt)
        #pragma unroll
        for (int nt = 0; nt < 4; ++nt)
            #pragma unroll
            for (int reg = 0; reg < 4; ++reg) {
                zz[mt][nt][reg] = 1.0f / (1.0f + __expf(-(acc2[mt][nt][reg] + bzv[nt])));
                float rr = 1.0f / (1.0f + __expf(-(acc2[mt][nt + 4][reg] + brv[nt])));
                float rhc = rr * acc1[mt][nt][reg];
                tr[wu][mt * 16 + 4 * q + reg][nt * 16 + r16] = (unsigned short)bf16r(rhc);
            }
    __builtin_amdgcn_wave_barrier();
    bf16x8 rhcA[2][2];
    #pragma unroll
    for (int mt = 0; mt < 2; ++mt)
        #pragma unroll
        for (int kf = 0; kf < 2; ++kf)
            rhcA[mt][kf] = asbf(*(const uint4*)&tr[wu][mt * 16 + r16][kf * 32 + 8 * q]);
    __builtin_amdgcn_wave_barrier();

    // ---- GEMM3: cand = [ic|r*hc] @ Wc  (K=128, N=64; B from LDS) ----
    f32x4 acc3[2][4];
    #pragma unroll
    for (int mt = 0; mt < 2; ++mt)
        #pragma unroll
        for (int nt = 0; nt < 4; ++nt)
            acc3[mt][nt] = (f32x4){0.0f, 0.0f, 0.0f, 0.0f};

    #pragma unroll
    for (int kf = 0; kf < 4; ++kf) {
        bf16x8 a[2];
        a[0] = (kf < 2) ? asbf(icA[0][kf]) : rhcA[0][kf - 2];
        a[1] = (kf < 2) ? asbf(icA[1][kf]) : rhcA[1][kf - 2];
        #pragma unroll
        for (int nt = 0; nt < 4; ++nt) {
            bf16x8 b = asbf(*(const uint4*)&s_wc[(nt * 16 + r16) * 68 + kf * 16 + q * 4]);
            #pragma unroll
            for (int mt = 0; mt < 2; ++mt)
                acc3[mt][nt] = __builtin_amdgcn_mfma_f32_16x16x32_bf16(a[mt], b, acc3[mt][nt], 0, 0, 0);
        }
    }

    // ---- epilogue: out = z*h + (1-z)*tanh(cand + bc); h from bf16 table ----
    float bcv[4];
    #pragma unroll
    for (int nt = 0; nt < 4; ++nt) bcv[nt] = bc[nt * 16 + r16];
    #pragma unroll
    for (int mt = 0; mt < 2; ++mt)
        #pragma unroll
        for (int nt = 0; nt < 4; ++nt)
            #pragma unroll
            for (int reg = 0; reg < 4; ++reg) {
                int node = base + mt * 16 + 4 * q + reg;
                if (node < N) {
                    float a = acc3[mt][nt][reg] + bcv[nt];
                    a = fminf(fmaxf(a, -40.0f), 40.0f);
                    float e = __expf(2.0f * a);
                    float ht = 1.0f - 2.0f / (e + 1.0f);
                    unsigned int hu = hbf[(size_t)node * 32 + nt * 8 + (r16 >> 1)];
                    float hv = (r16 & 1) ? hi2f(hu) : lo2f(hu);
                    float z = zz[mt][nt][reg];
                    out[(size_t)node * 64 + nt * 16 + r16] = z * hv + (1.0f - z) * ht;
                }
            }
}

extern "C" void kernel_launch(void* const* d_in, const int* in_sizes, int n_in,
                              void* d_out, int out_size, void* d_ws, size_t ws_size,
                              hipStream_t stream) {
    const float* x  = (const float*)d_in[0];
    const int*   ei = (const int*)  d_in[1];
    const float* h  = (const float*)d_in[2];
    const float* W1 = (const float*)d_in[3];
    const float* b1 = (const float*)d_in[4];
    const float* W2 = (const float*)d_in[5];
    const float* b2 = (const float*)d_in[6];
    const float* Wz = (const float*)d_in[7];
    const float* bz = (const float*)d_in[8];
    const float* Wr = (const float*)d_in[9];
    const float* br = (const float*)d_in[10];
    const float* Wc = (const float*)d_in[11];
    const float* bc = (const float*)d_in[12];
    float* out = (float*)d_out;

    int N = in_sizes[0] / 2;     // 100000
    int E = in_sizes[1] / 2;     // 1600000

    // workspace layout (u32 units):
    //   dinv N | row N | cnt N | txa 2N | txb 2N | bs 1024 | WT 18432
    //   | cntsc 2*NBN | scanned 2*NBN | srcu E
    //   O (64-B aligned): hbf 32N | bufA 32N | hpp 32N
    //   build temps alias hbf span: dstrec E | srckeys E  (= 2E = 32N exactly)
    //   total ~ 7N + 19456 + 4*NBN + E + 96N  ~= 49.8 MB
    char* wsb = (char*)d_ws;
    float* dinv = (float*)wsb;                                   // N
    int*   row  = (int*)  (wsb + (size_t)N * 4);                 // N
    int*   cnt  = (int*)  (wsb + (size_t)2 * N * 4);             // N
    float* txa  = (float*)(wsb + (size_t)3 * N * 4);             // 2N
    float* txb  = (float*)(wsb + (size_t)5 * N * 4);             // 2N
    int*   bs   = (int*)  (wsb + (size_t)7 * N * 4);             // 1024
    unsigned int* WT = (unsigned int*)(wsb + ((size_t)7 * N + 1024) * 4);      // 18432
    int*   cntsc   = (int*)(wsb + ((size_t)7 * N + 19456) * 4);                // 2*NBN
    int*   scanned = (int*)(wsb + ((size_t)7 * N + 19456 + 2 * NBN) * 4);      // 2*NBN
    unsigned int* srcu = (unsigned int*)(wsb + ((size_t)7 * N + 19456 + 4 * NBN) * 4); // E
    size_t O = (size_t)7 * N + 19456 + 4 * (size_t)NBN + (size_t)E;
    unsigned int* hbf  = (unsigned int*)(wsb + O * 4);                         // 32N
    unsigned int* bufA = (unsigned int*)(wsb + (O + (size_t)32 * N) * 4);      // 32N
    unsigned int* hpp  = (unsigned int*)(wsb + (O + (size_t)64 * N) * 4);      // 32N
    unsigned int* dstrec = (unsigned int*)(wsb + O * 4);                       // E (alias)
    int* srckeys = (int*)(wsb + (O + (size_t)E) * 4);                          // E (alias)

    // ---- bucketed CSR build (no global atomics, no memset) ----
    bucketA_kernel<<<NBA, 256, 0, stream>>>(ei, E, cntsc);
    int scn = 2 * NBN;
    scanA_kernel<<<scn / 256, 256, 0, stream>>>(cntsc, bs, scn);
    scanB_kernel<<<1, 1024, 0, stream>>>(bs, scn / 256);
    scanC_kernel<<<scn / 256, 256, 0, stream>>>(cntsc, bs, scanned, scn);
    bucketB_kernel<<<NBA, 256, 0, stream>>>(ei, E, scanned, dstrec, srckeys);
    bucketC2_kernel<<<NBUCK, BINS, 0, stream>>>(srckeys, scanned, dinv, N, E);
    bucketC1_kernel<<<NBUCK, BINS, 0, stream>>>(dstrec, scanned, row, cnt, srcu, N, E);

    // packs (hbf overwrites dead build temps after C1/C2)
    packwT_kernel<<<(18432 + 255) / 256, 256, 0, stream>>>(W2, Wz, Wr, Wc, WT);
    packh_kernel <<<(32 * N + 255) / 256, 256, 0, stream>>>(h, hbf, 32 * N);

    // fused hidden+input propagation: [hbf|x] -> [bufA|txa] -> [hpp|txb]
    int gblocks = (N + 3) / 4;
    gather64_kernel<<<gblocks, 256, 0, stream>>>(row, cnt, srcu, dinv, hbf,
                                                 (const float2*)x, bufA,
                                                 (float2*)txa, N);
    gather64_kernel<<<gblocks, 256, 0, stream>>>(row, cnt, srcu, dinv, bufA,
                                                 (const float2*)txa, hpp,
                                                 (float2*)txb, N);

    // fused MFMA gate (4 waves/block, 128 nodes; WzrT/WcT staged in LDS)
    int gateblocks = (N + 127) / 128;
    gate_mfma_kernel<<<gateblocks, 256, 0, stream>>>(
        out, x, hbf, txa, txb, bufA, hpp, W1, b1, WT, b2, bz, br, bc, N);
}